// Round 2
// baseline (584.211 us; speedup 1.0000x reference)
//
#include <hip/hip_runtime.h>

// out_fp = (a*scale_a)*(b*scale_b); out_q = clip(rint(out_fp/scale_out), -128, 127)
// a,b int8-in-reference delivered as int32 (const int*), N = 16*4096*1024 = 67108864.
// scales float32 (D=1024). d_out = float[N] quantized values ++ float[D] scale_out.
//
// R1: 1x vec4/thread, plain ld/st -> mulq 176 us (4.6 TB/s demand).
// R3: UNROLL4 + nt stores -> 208 us (regression; mostly nt stores per R5 result).
// R4: R1 + nt LOADS -> bench 558; mulq <163 us (~5.0 TB/s demand).
// R5: ILP-4 -> 568.9, NEUTRAL. Lesson: per-wave ILP adds nothing at full TLP;
//     memory system already saturated with outstanding requests.
// R6 (this): single fused persistent kernel.
//     - prep_scales fused in: per-thread c = sa*sb/so (same IEEE expr, bit-identical),
//       computed ONCE because grid-stride step (2048*256*4 = 2M elem) % D == 0
//       -> column index invariant across iterations. Zero table loads in hot loop.
//     - 2048 blocks x 256 thr = 32 waves/CU exactly resident, grid-stride x32.
//     - removes prep kernel + inter-kernel gap (2 launches -> 1 per iteration).
//     - nt loads kept (R4 win), plain stores kept (R3/R5 lesson).
//     Predict: one ~150-160 us dispatch/iter, dur_us 568 -> ~450-520.

typedef int   vi4 __attribute__((ext_vector_type(4)));
typedef float vf4 __attribute__((ext_vector_type(4)));

#define TPB      256
#define MAX_BLK  2048   // 8 blocks/CU * 256 CU -> 32 waves/CU, fully resident

__device__ __forceinline__ float qclamp(int p, float cs) {
    return fminf(fmaxf(rintf((float)p * cs), -128.0f), 127.0f);
}

__global__ __launch_bounds__(TPB) void fused_mulq_kernel(
    const vi4*  __restrict__ a,
    const vi4*  __restrict__ b,
    const float* __restrict__ sa,
    const float* __restrict__ sb,
    const float* __restrict__ so,
    vf4*  __restrict__ out,
    float* __restrict__ out_tail,
    unsigned dmask,      // D-1 (valid when D pow2)
    unsigned colreuse,   // 1 iff D pow2 && (grid stride in elems) % D == 0
    unsigned D, unsigned nvec)
{
    const unsigned stride = gridDim.x * (unsigned)TPB;   // vec4s per grid pass
    unsigned idx0 = blockIdx.x * (unsigned)TPB + threadIdx.x;

    // Second tuple output: scale_out passthrough (4 KiB), block 0 only.
    if (blockIdx.x == 0) {
        unsigned t4 = threadIdx.x * 4u;
        if (t4 < D) *(float4*)(out_tail + t4) = *(const float4*)(so + t4);
    }

    if (colreuse) {
        // Column is invariant across the grid-stride loop: compute the
        // combined scale once per thread. Same IEEE expr as the old
        // prep_scales kernel -> bit-identical results.
        unsigned col = (idx0 * 4u) & dmask;
        float4 sa4 = *(const float4*)(sa + col);   // 4 KiB tables, L2-broadcast
        float4 sb4 = *(const float4*)(sb + col);
        float4 so4 = *(const float4*)(so + col);
        float cx = sa4.x * sb4.x / so4.x;
        float cy = sa4.y * sb4.y / so4.y;
        float cz = sa4.z * sb4.z / so4.z;
        float cw = sa4.w * sb4.w / so4.w;

        for (unsigned idx = idx0; idx < nvec; idx += stride) {
            vi4 av = __builtin_nontemporal_load(&a[idx]);   // read-once streams
            vi4 bv = __builtin_nontemporal_load(&b[idx]);
            vf4 o;
            o.x = qclamp(__mul24(av.x, bv.x), cx);  // int8*int8 fits 24-bit
            o.y = qclamp(__mul24(av.y, bv.y), cy);
            o.z = qclamp(__mul24(av.z, bv.z), cz);
            o.w = qclamp(__mul24(av.w, bv.w), cw);
            out[idx] = o;                           // plain store (L3-friendly)
        }
    } else {
        // Generic fallback (not taken at B=16,S=4096,D=1024).
        for (unsigned idx = idx0; idx < nvec; idx += stride) {
            unsigned col = (idx * 4u) % D;
            float4 sa4 = *(const float4*)(sa + col);
            float4 sb4 = *(const float4*)(sb + col);
            float4 so4 = *(const float4*)(so + col);
            vi4 av = __builtin_nontemporal_load(&a[idx]);
            vi4 bv = __builtin_nontemporal_load(&b[idx]);
            vf4 o;
            o.x = qclamp(__mul24(av.x, bv.x), sa4.x * sb4.x / so4.x);
            o.y = qclamp(__mul24(av.y, bv.y), sa4.y * sb4.y / so4.y);
            o.z = qclamp(__mul24(av.z, bv.z), sa4.z * sb4.z / so4.z);
            o.w = qclamp(__mul24(av.w, bv.w), sa4.w * sb4.w / so4.w);
            out[idx] = o;
        }
    }
}

extern "C" void kernel_launch(void* const* d_in, const int* in_sizes, int n_in,
                              void* d_out, int out_size, void* d_ws, size_t ws_size,
                              hipStream_t stream) {
    const int*   a  = (const int*)  d_in[0];
    const float* sa = (const float*)d_in[1];
    const int*   b  = (const int*)  d_in[2];
    const float* sb = (const float*)d_in[3];
    const float* so = (const float*)d_in[4];

    const int N = in_sizes[0];   // 67108864
    const int D = in_sizes[1];   // 1024

    float* out = (float*)d_out;

    const unsigned nvec = (unsigned)(N / 4);
    unsigned nblocks = (nvec + (unsigned)TPB - 1u) / (unsigned)TPB;
    if (nblocks > (unsigned)MAX_BLK) nblocks = (unsigned)MAX_BLK;

    const unsigned pow2     = ((D & (D - 1)) == 0) ? 1u : 0u;
    const unsigned stride_e = nblocks * (unsigned)TPB * 4u;  // elems per grid pass
    const unsigned colreuse = (pow2 && (stride_e % (unsigned)D) == 0u) ? 1u : 0u;

    fused_mulq_kernel<<<nblocks, TPB, 0, stream>>>(
        (const vi4*)a, (const vi4*)b, sa, sb, so,
        (vf4*)out, out + (size_t)N,
        (unsigned)(D - 1), colreuse, (unsigned)D, nvec);
}

// Round 3
// 583.150 us; speedup vs baseline: 1.0018x; 1.0018x over previous
//
#include <hip/hip_runtime.h>

// out_fp = (a*scale_a)*(b*scale_b); out_q = clip(rint(out_fp/scale_out), -128, 127)
// a,b int8-valued int32 (const int*), N = 16*4096*1024 = 67108864.
// scales float32 (D=1024). d_out = float[N] quantized values ++ float[D] scale_out.
//
// R1: 1x vec4/thread, plain ld/st -> mulq 176 us (4.6 TB/s demand).
// R3: UNROLL4 + nt stores -> 208 us. Mechanism (understood in R6 post-mortem):
//     nt stores bypass L3, so resident dirty poison lines drain to HBM *and*
//     our writes land -> double write traffic. Plain stores overwrite resident
//     poison and cancel its writeback.
// R4: R1 + nt LOADS -> bench 558; mulq ~160 us.
// R5: ILP-4 -> 568.9 NEUTRAL. Per-wave ILP adds nothing at full TLP.
// R6: fused persistent (2048 blk) -> 584.2; kernel 163.8 us, FETCH 268 MB
//     (half of mandatory 537!), WRITE 268 MB, VALUBusy 7%. Structural
//     invariance at ~164 us across R1/R4/R5/R6 => limiter is OUTSIDE the
//     instruction stream: the harness's 1.07 GB (4x!) poison fill drains
//     dirty L3 lines DURING our kernel, stealing HBM BW.
// R7 (this): REVERSE sweep order (single-variable diff vs R6).
//     Fill leaves the HIGH ~256 MB of output dirty-resident in L3; drain is
//     LRU low-first. Forward sweep arrives after drain (no cancellation).
//     Reverse sweep overwrites dirty-resident poison first -> cancels up to
//     ~250 MB of HBM writeback per iteration.
//     Predict: dur_us 584 -> ~470-520; kernel counters ~unchanged.

typedef int   vi4 __attribute__((ext_vector_type(4)));
typedef float vf4 __attribute__((ext_vector_type(4)));

#define TPB      256
#define MAX_BLK  2048   // 8 blocks/CU * 256 CU -> 32 waves/CU, fully resident

__device__ __forceinline__ float qclamp(int p, float cs) {
    return fminf(fmaxf(rintf((float)p * cs), -128.0f), 127.0f);
}

__global__ __launch_bounds__(TPB) void fused_mulq_kernel(
    const vi4*  __restrict__ a,
    const vi4*  __restrict__ b,
    const float* __restrict__ sa,
    const float* __restrict__ sb,
    const float* __restrict__ so,
    vf4*  __restrict__ out,
    float* __restrict__ out_tail,
    unsigned dmask,      // D-1 (valid when D pow2)
    unsigned colreuse,   // 1 iff D pow2 && (grid stride in elems) % D == 0
    unsigned D, unsigned nvec)
{
    const unsigned stride = gridDim.x * (unsigned)TPB;   // vec4s per grid pass
    // Reverse block order: highest addresses processed by the first-dispatched
    // blocks, wave-internal lane order still ascending (coalescing intact).
    const unsigned bid  = gridDim.x - 1u - blockIdx.x;
    const unsigned idx0 = bid * (unsigned)TPB + threadIdx.x;

    // Second tuple output: scale_out passthrough (4 KiB).
    if (blockIdx.x == 0) {
        unsigned t4 = threadIdx.x * 4u;
        if (t4 < D) *(float4*)(out_tail + t4) = *(const float4*)(so + t4);
    }

    if (idx0 >= nvec) return;

    if (colreuse) {
        // Column invariant across grid-stride steps (stride % D == 0):
        // combined scale computed once per thread, same IEEE expr as the
        // original prep_scales kernel -> bit-identical.
        unsigned col = (idx0 * 4u) & dmask;
        float4 sa4 = *(const float4*)(sa + col);
        float4 sb4 = *(const float4*)(sb + col);
        float4 so4 = *(const float4*)(so + col);
        float cx = sa4.x * sb4.x / so4.x;
        float cy = sa4.y * sb4.y / so4.y;
        float cz = sa4.z * sb4.z / so4.z;
        float cw = sa4.w * sb4.w / so4.w;

        // Descending grid-stride loop: start at this thread's HIGHEST index.
        unsigned idx = idx0 + ((nvec - 1u - idx0) / stride) * stride;
        while (true) {
            vi4 av = __builtin_nontemporal_load(&a[idx]);   // read-once streams
            vi4 bv = __builtin_nontemporal_load(&b[idx]);
            vf4 o;
            o.x = qclamp(__mul24(av.x, bv.x), cx);  // int8*int8 fits 24-bit
            o.y = qclamp(__mul24(av.y, bv.y), cy);
            o.z = qclamp(__mul24(av.z, bv.z), cz);
            o.w = qclamp(__mul24(av.w, bv.w), cw);
            out[idx] = o;           // plain store: overwrite resident poison,
                                    // cancel its writeback (R3 lesson inverted)
            if (idx == idx0) break;
            idx -= stride;
        }
    } else {
        // Generic fallback (not taken at B=16,S=4096,D=1024).
        unsigned idx = idx0 + ((nvec - 1u - idx0) / stride) * stride;
        while (true) {
            unsigned col = (idx * 4u) % D;
            float4 sa4 = *(const float4*)(sa + col);
            float4 sb4 = *(const float4*)(sb + col);
            float4 so4 = *(const float4*)(so + col);
            vi4 av = __builtin_nontemporal_load(&a[idx]);
            vi4 bv = __builtin_nontemporal_load(&b[idx]);
            vf4 o;
            o.x = qclamp(__mul24(av.x, bv.x), sa4.x * sb4.x / so4.x);
            o.y = qclamp(__mul24(av.y, bv.y), sa4.y * sb4.y / so4.y);
            o.z = qclamp(__mul24(av.z, bv.z), sa4.z * sb4.z / so4.z);
            o.w = qclamp(__mul24(av.w, bv.w), sa4.w * sb4.w / so4.w);
            out[idx] = o;
            if (idx == idx0) break;
            idx -= stride;
        }
    }
}

extern "C" void kernel_launch(void* const* d_in, const int* in_sizes, int n_in,
                              void* d_out, int out_size, void* d_ws, size_t ws_size,
                              hipStream_t stream) {
    const int*   a  = (const int*)  d_in[0];
    const float* sa = (const float*)d_in[1];
    const int*   b  = (const int*)  d_in[2];
    const float* sb = (const float*)d_in[3];
    const float* so = (const float*)d_in[4];

    const int N = in_sizes[0];   // 67108864
    const int D = in_sizes[1];   // 1024

    float* out = (float*)d_out;

    const unsigned nvec = (unsigned)(N / 4);
    unsigned nblocks = (nvec + (unsigned)TPB - 1u) / (unsigned)TPB;
    if (nblocks > (unsigned)MAX_BLK) nblocks = (unsigned)MAX_BLK;

    const unsigned pow2     = ((D & (D - 1)) == 0) ? 1u : 0u;
    const unsigned stride_e = nblocks * (unsigned)TPB * 4u;  // elems per grid pass
    const unsigned colreuse = (pow2 && (stride_e % (unsigned)D) == 0u) ? 1u : 0u;

    fused_mulq_kernel<<<nblocks, TPB, 0, stream>>>(
        (const vi4*)a, (const vi4*)b, sa, sb, so,
        (vf4*)out, out + (size_t)N,
        (unsigned)(D - 1), colreuse, (unsigned)D, nvec);
}

// Round 4
// 566.257 us; speedup vs baseline: 1.0317x; 1.0298x over previous
//
#include <hip/hip_runtime.h>

// out_fp = (a*scale_a)*(b*scale_b); out_q = clip(rint(out_fp/scale_out), -128, 127)
// a,b int8-valued int32 (const int*), N = 16*4096*1024 = 67108864.
// scales float32 (D=1024). d_out = float[N] quantized values ++ float[D] scale_out.
//
// ---- session journal ----
// R1: 1x vec4/thread, plain ld/st -> mulq 176 us (4.6 TB/s demand).
// R3: UNROLL4 + nt stores -> 208 us. nt stores bypass L3: resident dirty
//     poison drains to HBM *in addition to* our writes. Plain stores
//     overwrite resident poison and cancel its writeback.
// R4: R1 + nt LOADS -> 558.5 us total; mulq ~160 us.  <-- BEST
// R5: ILP-4 (8 loads in flight/wave) -> 568.9 NEUTRAL. Not MLP-bound.
// R6: fused persistent 2048-blk -> 584.2. Kernel 163.8 us, FETCH 268 MB
//     (= exactly half of the 537 MB mandatory reads: constant inputs are
//     ~50% L3-resident across iterations), WRITE 268 MB, VALUBusy 7%.
// R7: reverse sweep (poison-writeback cancellation by order) -> 583.2 NEUTRAL.
// R8 (this): revert to R4 exactly — lock in best measured structure.
//     One-shot 65K-block grid beat persistent-2048 in both pairs
//     (558.5/568.9 vs 584.2/583.2).
//
// ROOFLINE ARITHMETIC (why this is the floor): mandatory traffic/iter =
// 537 MB read + 268 MB write = 805 MB; ~268 MB of reads served by L3
// residency; remaining ~537 MB HBM demand shares a bus that the harness's
// 1.07 GB poison-fill drain keeps saturated at the 6.3-6.6 TB/s empirical
// ceiling during our window (kernel 537 MB + drain ~0.5 GB ~= 164 us x 6.3).
// Four structurally independent kernels (R4-R7) land within 4.6%; nt-store,
// sweep-order, ILP, persistence, and fusion levers all exhausted.

typedef int   vi4 __attribute__((ext_vector_type(4)));
typedef float vf4 __attribute__((ext_vector_type(4)));

__global__ void prep_scales_kernel(const float* __restrict__ sa,
                                   const float* __restrict__ sb,
                                   const float* __restrict__ so,
                                   float* __restrict__ c,
                                   float* __restrict__ out_tail,
                                   int D) {
    int d = blockIdx.x * blockDim.x + threadIdx.x;
    if (d < D) {
        float s = so[d];
        c[d] = sa[d] * sb[d] / s;   // exact IEEE divide, once per column
        out_tail[d] = s;            // second tuple output: scale_out passthrough
    }
}

__global__ __launch_bounds__(256) void mulq_kernel(const vi4* __restrict__ a,
                                                   const vi4* __restrict__ b,
                                                   const float* __restrict__ c,
                                                   vf4* __restrict__ out,
                                                   unsigned dmask, unsigned use_mask,
                                                   unsigned D, unsigned nvec) {
    unsigned tid = blockIdx.x * blockDim.x + threadIdx.x;
    if (tid >= nvec) return;
    unsigned e0 = tid * 4u;                          // first element index
    unsigned d = use_mask ? (e0 & dmask) : (e0 % D); // column index (mult of 4)

    vi4 av = __builtin_nontemporal_load(&a[tid]);    // read-once: no L2/L3 alloc
    vi4 bv = __builtin_nontemporal_load(&b[tid]);
    float4 cv = *(const float4*)(c + d);             // 4 KiB table, cache-resident

    vf4 o;
    o.x = fminf(fmaxf(rintf((float)(av.x * bv.x) * cv.x), -128.0f), 127.0f);
    o.y = fminf(fmaxf(rintf((float)(av.y * bv.y) * cv.y), -128.0f), 127.0f);
    o.z = fminf(fmaxf(rintf((float)(av.z * bv.z) * cv.z), -128.0f), 127.0f);
    o.w = fminf(fmaxf(rintf((float)(av.w * bv.w) * cv.w), -128.0f), 127.0f);

    out[tid] = o;                                    // plain store (L3-friendly:
                                                     // overwrites resident poison,
                                                     // cancels its writeback)
}

extern "C" void kernel_launch(void* const* d_in, const int* in_sizes, int n_in,
                              void* d_out, int out_size, void* d_ws, size_t ws_size,
                              hipStream_t stream) {
    const int*   a  = (const int*)  d_in[0];
    const float* sa = (const float*)d_in[1];
    const int*   b  = (const int*)  d_in[2];
    const float* sb = (const float*)d_in[3];
    const float* so = (const float*)d_in[4];

    const int N = in_sizes[0];   // 67108864
    const int D = in_sizes[1];   // 1024

    float* out = (float*)d_out;
    float* c   = (float*)d_ws;   // D floats of scratch (4 KiB)

    prep_scales_kernel<<<(D + 255) / 256, 256, 0, stream>>>(sa, sb, so, c, out + (size_t)N, D);

    const unsigned nvec = (unsigned)(N / 4);
    const unsigned use_mask = ((D & (D - 1)) == 0) ? 1u : 0u;
    mulq_kernel<<<(nvec + 255u) / 256u, 256, 0, stream>>>(
        (const vi4*)a, (const vi4*)b, c, (vf4*)out,
        (unsigned)(D - 1), use_mask, (unsigned)D, nvec);
}